// Round 6
// baseline (151.374 us; speedup 1.0000x reference)
//
#include <hip/hip_runtime.h>
#include <hip/hip_bf16.h>

// out[i] = 0.999f * a[i*K + (int)z[i*D + attr_index]]
// B = 4194304, D = 32, K = 16.
//
// Memory-system-bound dual scattered stream. Round-5 structure + NT hints,
// ROWS 8 -> 16 to double per-thread MLP (32 outstanding 4B loads/thread),
// grid 1024 blocks = 4096 waves (16/CU) -- probes byte-bound vs MLP-bound.

#define D_DIM 32
#define K_DIM 16
#define SCALE 0.999f
#define ROWS  16   // rows per thread

typedef float f32x4 __attribute__((ext_vector_type(4)));

__global__ __launch_bounds__(256) void gather_valuation_kernel(
    const float* __restrict__ z,
    const float* __restrict__ a,
    const int* __restrict__ attr_p,
    float* __restrict__ out,
    int B)
{
    const int attr = attr_p[0];
    const long t    = (long)blockIdx.x * blockDim.x + threadIdx.x;
    const long base = t * ROWS;
    if (base >= B) return;

    // 16 independent z column loads (4B each, stride 128B), non-temporal
    float zv[ROWS];
#pragma unroll
    for (int j = 0; j < ROWS; ++j)
        zv[j] = __builtin_nontemporal_load(&z[(base + j) * D_DIM + attr]);

    // 16 independent a gathers (4B each), non-temporal; compiler issues
    // gather j as soon as zv[j] lands (incremental vmcnt waits).
    float g[ROWS];
#pragma unroll
    for (int j = 0; j < ROWS; ++j) {
        const int idx = (int)zv[j];
        g[j] = __builtin_nontemporal_load(&a[(base + j) * K_DIM + idx]);
    }

    // Four coalesced 16B stores, non-temporal
    f32x4* o4 = (f32x4*)(out + base);
#pragma unroll
    for (int q = 0; q < ROWS / 4; ++q) {
        f32x4 r;
        r.x = g[4 * q + 0] * SCALE;
        r.y = g[4 * q + 1] * SCALE;
        r.z = g[4 * q + 2] * SCALE;
        r.w = g[4 * q + 3] * SCALE;
        __builtin_nontemporal_store(r, &o4[q]);
    }
}

extern "C" void kernel_launch(void* const* d_in, const int* in_sizes, int n_in,
                              void* d_out, int out_size, void* d_ws, size_t ws_size,
                              hipStream_t stream)
{
    const float* z    = (const float*)d_in[0];
    const float* a    = (const float*)d_in[1];
    const int*   attr = (const int*)d_in[2];
    float*       out  = (float*)d_out;

    const int B = out_size;  // 4194304 = 256 * 16 * 1024

    const int block = 256;
    const int grid  = (B + block * ROWS - 1) / (block * ROWS);  // 1024

    gather_valuation_kernel<<<grid, block, 0, stream>>>(z, a, attr, out, B);
}

// Round 7
// 136.106 us; speedup vs baseline: 1.1122x; 1.1122x over previous
//
#include <hip/hip_runtime.h>
#include <hip/hip_bf16.h>

// out[i] = 0.999f * a[i*K + (int)z[i*D + attr_index]]
// B = 4194304, D = 32, K = 16.
//
// FINAL (round-5 optimum, reverted after ROWS=16 regression probe):
// Memory-system-bound dual scattered stream, ~784 MB of 128B-line traffic
// -> ~5.8 TB/s effective (~92% of achievable). Minimal requests per element
// (one 4B z load, one 4B a load, 1/4 float4 store), 8 rows/thread ILP,
// 2048 blocks (32 waves/CU TLP), non-temporal hints (stream-once data,
// skip L2 allocation: -8% measured).
// Probed and rejected: speculative full-row a-load (+55%), ROWS=16 MLP
// (+12%), plain vs NT (+8%).

#define D_DIM 32
#define K_DIM 16
#define SCALE 0.999f
#define ROWS  8   // rows per thread

typedef float f32x4 __attribute__((ext_vector_type(4)));

__global__ __launch_bounds__(256) void gather_valuation_kernel(
    const float* __restrict__ z,
    const float* __restrict__ a,
    const int* __restrict__ attr_p,
    float* __restrict__ out,
    int B)
{
    const int attr = attr_p[0];
    const long t    = (long)blockIdx.x * blockDim.x + threadIdx.x;
    const long base = t * ROWS;
    if (base >= B) return;

    // 8 independent z column loads (4B each, stride 128B), non-temporal
    float zv[ROWS];
#pragma unroll
    for (int j = 0; j < ROWS; ++j)
        zv[j] = __builtin_nontemporal_load(&z[(base + j) * D_DIM + attr]);

    // 8 independent a gathers (4B each), non-temporal
    float g[ROWS];
#pragma unroll
    for (int j = 0; j < ROWS; ++j) {
        const int idx = (int)zv[j];
        g[j] = __builtin_nontemporal_load(&a[(base + j) * K_DIM + idx]);
    }

    // Two coalesced 16B stores, non-temporal
    f32x4 r0, r1;
    r0.x = g[0] * SCALE; r0.y = g[1] * SCALE;
    r0.z = g[2] * SCALE; r0.w = g[3] * SCALE;
    r1.x = g[4] * SCALE; r1.y = g[5] * SCALE;
    r1.z = g[6] * SCALE; r1.w = g[7] * SCALE;
    f32x4* o4 = (f32x4*)(out + base);
    __builtin_nontemporal_store(r0, &o4[0]);
    __builtin_nontemporal_store(r1, &o4[1]);
}

extern "C" void kernel_launch(void* const* d_in, const int* in_sizes, int n_in,
                              void* d_out, int out_size, void* d_ws, size_t ws_size,
                              hipStream_t stream)
{
    const float* z    = (const float*)d_in[0];
    const float* a    = (const float*)d_in[1];
    const int*   attr = (const int*)d_in[2];
    float*       out  = (float*)d_out;

    const int B = out_size;  // 4194304 = 256 * 8 * 2048

    const int block = 256;
    const int grid  = (B + block * ROWS - 1) / (block * ROWS);  // 2048

    gather_valuation_kernel<<<grid, block, 0, stream>>>(z, a, attr, out, B);
}